// Round 7
// baseline (123.324 us; speedup 1.0000x reference)
//
#include <hip/hip_runtime.h>
#include <hip/hip_bf16.h>

// r7: two-phase. Prep kernel converts the whole image ONCE (coalesced) into a
// channel-last per-pixel record (112 B): {32x masked bf16 msi, eA[8], eB[8], pad}.
// Patch kernel stages 6 contiguous 16B loads/thread -> LDS -> r4 MFMA math:
//   MFMA1: A = -2*m*msi~, B = m*msi~                     -> -2 m m g_m
//   MFMA2: A = m*{2h~,s_hi,s_lo,1,1,0}, B = m*{h~,1,1,s_hi,s_lo,0}
//          -> m m (2 g_h + s_p + s_q)
// acc += |g[reg]|; partials -> d_ws; tiny reduce kernel writes out.

#define PSZ  256
#define IMG  512
#define IMG2 (IMG * IMG)
#define REC  56          // ushorts per pixel record = 112 B (16B-aligned, 2-way LDS banks)

typedef __attribute__((ext_vector_type(8))) short short8;
typedef __attribute__((ext_vector_type(4))) float float4v;

static __device__ __forceinline__ unsigned short f2bf(float v) {
    union { __hip_bfloat16 b; unsigned short u; } cv;
    cv.b = __float2bfloat16(v);
    return cv.u;
}
static __device__ __forceinline__ float bf2f(unsigned short u) {
    union { unsigned int u; float f; } cv;
    cv.u = ((unsigned int)u) << 16;
    return cv.f;
}

// ---- phase 1: whole-image convert, fully coalesced ----
__global__ __launch_bounds__(256, 4)
void prep_kernel(const float* __restrict__ msi,
                 const float* __restrict__ he,
                 unsigned short* __restrict__ rec)
{
    const int idx = blockIdx.x * 256 + threadIdx.x;    // pixel id, 512*512 total

    const float h0 = he[idx], h1 = he[IMG2 + idx], h2 = he[2 * IMG2 + idx];
    float v[32];
#pragma unroll
    for (int ch = 0; ch < 32; ++ch) v[ch] = msi[(size_t)ch * IMG2 + idx];

    const float mf = (h0 + h1 + h2 >= 0.05f) ? 1.f : 0.f;     // mask: exact fp32
    const unsigned short hb0 = f2bf(h0 * mf), hb1 = f2bf(h1 * mf), hb2 = f2bf(h2 * mf);
    const float hr0 = bf2f(hb0), hr1 = bf2f(hb1), hr2 = bf2f(hb2);
    const float sh = hr0 * hr0 + hr1 * hr1 + hr2 * hr2;

    float sm = 0.f;
    unsigned int pk[16];
#pragma unroll
    for (int k = 0; k < 16; ++k) {
        unsigned short lo = f2bf(v[2 * k]     * mf);
        unsigned short hi = f2bf(v[2 * k + 1] * mf);
        float fl = bf2f(lo), fh = bf2f(hi);
        sm = fmaf(fl, fl, sm);
        sm = fmaf(fh, fh, sm);
        pk[k] = (unsigned int)lo | ((unsigned int)hi << 16);
    }
    const float s = sm - sh;                  // masked already (m^2 = m)
    const unsigned short shi = f2bf(s);
    const unsigned short slo = f2bf(s - bf2f(shi));
    const unsigned short mb  = (mf != 0.f) ? (unsigned short)0x3F80 : (unsigned short)0;
    const unsigned short d0  = f2bf(2.f * hr0);   // exact: exponent+1
    const unsigned short d1  = f2bf(2.f * hr1);
    const unsigned short d2  = f2bf(2.f * hr2);

    unsigned short* rp = rec + (size_t)idx * REC;
#pragma unroll
    for (int k = 0; k < 4; ++k)               // ch 0..31 (masked bf16)
        *(uint4*)(rp + k * 8) = make_uint4(pk[4 * k], pk[4 * k + 1],
                                           pk[4 * k + 2], pk[4 * k + 3]);
    *(uint4*)(rp + 32) = make_uint4(          // eA = {2h0,2h1,2h2,s_hi,s_lo,m,m,0}
        (unsigned)d0 | ((unsigned)d1 << 16),
        (unsigned)d2 | ((unsigned)shi << 16),
        (unsigned)slo | ((unsigned)mb << 16),
        (unsigned)mb);
    *(uint4*)(rp + 40) = make_uint4(          // eB = {h0,h1,h2,m,m,s_hi,s_lo,0}
        (unsigned)hb0 | ((unsigned)hb1 << 16),
        (unsigned)hb2 | ((unsigned)mb << 16),
        (unsigned)mb | ((unsigned)shi << 16),
        (unsigned)slo);
    // rp[48..55] pad: never read
}

// ---- phase 2: per-patch MFMA ----
__global__ __launch_bounds__(256, 4)
void corr_loss_kernel(const unsigned short* __restrict__ rec,
                      const int* __restrict__ i_idx,
                      const int* __restrict__ j_idx,
                      float* __restrict__ partial)
{
    __shared__ __align__(16) unsigned short xs[PSZ * REC];   // 28672 B
    __shared__ float red[4];

    const int b = blockIdx.x;
    const int t = threadIdx.x;
    const int i0 = i_idx[b], j0 = j_idx[b];

    // stage pixel p = t: 6 contiguous 16B loads (rows are full 1792B runs)
    {
        const int r = t >> 4, c = t & 15;
        const unsigned short* gp =
            rec + (size_t)((i0 + r) * IMG + (j0 + c)) * REC;
        uint4 u[6];
#pragma unroll
        for (int k = 0; k < 6; ++k) u[k] = *(const uint4*)(gp + k * 8);
#pragma unroll
        for (int k = 0; k < 6; ++k) *(uint4*)&xs[t * REC + k * 8] = u[k];
    }
    __syncthreads();

    const int lane = t & 63, w = t >> 6;
    const int mrow = lane & 15, quad = lane >> 4;
    const short8 zfrag = {0, 0, 0, 0, 0, 0, 0, 0};

    // hoist A-frags; on-the-fly x~ -> -2*x~ (sign flip + exp+1, 0 <= x < 2)
    short8 Am[4], Ah[4];
#pragma unroll
    for (int ii = 0; ii < 4; ++ii) {
        const int ri = ((w << 2) + ii) * 16 + mrow;
        uint4 u = *(const uint4*)&xs[ri * REC + (quad << 3)];
        u.x = (u.x ^ 0x80008000u) + 0x00800080u;
        u.y = (u.y ^ 0x80008000u) + 0x00800080u;
        u.z = (u.z ^ 0x80008000u) + 0x00800080u;
        u.w = (u.w ^ 0x80008000u) + 0x00800080u;
        Am[ii] = *(const short8*)&u;
        Ah[ii] = (quad == 0) ? *(const short8*)&xs[ri * REC + 32] : zfrag;
    }

    float acc[4] = {0.f, 0.f, 0.f, 0.f};
#pragma unroll 4
    for (int j = 0; j < 16; ++j) {
        const int cj = (j << 4) + mrow;
        short8 Bm = *(const short8*)&xs[cj * REC + (quad << 3)];
        short8 Bh = (quad == 0) ? *(const short8*)&xs[cj * REC + 40] : zfrag;
        float4v g[4];
#pragma unroll
        for (int ii = 0; ii < 4; ++ii) {
            g[ii] = (float4v){0.f, 0.f, 0.f, 0.f};
            g[ii] = __builtin_amdgcn_mfma_f32_16x16x32_bf16(Ah[ii], Bh, g[ii], 0, 0, 0);
            g[ii] = __builtin_amdgcn_mfma_f32_16x16x32_bf16(Am[ii], Bm, g[ii], 0, 0, 0);
        }
#pragma unroll
        for (int ii = 0; ii < 4; ++ii) {
            acc[ii] += fabsf(g[ii][0]);
            acc[ii] += fabsf(g[ii][1]);
            acc[ii] += fabsf(g[ii][2]);
            acc[ii] += fabsf(g[ii][3]);
        }
    }
    float a = (acc[0] + acc[1]) + (acc[2] + acc[3]);

#pragma unroll
    for (int off = 32; off > 0; off >>= 1)
        a += __shfl_down(a, off, 64);
    if (lane == 0) red[w] = a;
    __syncthreads();
    if (t == 0)
        partial[b] = (red[0] + red[1]) + (red[2] + red[3]);
}

__global__ __launch_bounds__(256)
void reduce_kernel(const float* __restrict__ partial, float* __restrict__ out,
                   int n, float scale)
{
    __shared__ float red[4];
    float a = 0.f;
    for (int i = threadIdx.x; i < n; i += 256) a += partial[i];
#pragma unroll
    for (int off = 32; off > 0; off >>= 1)
        a += __shfl_down(a, off, 64);
    const int lane = threadIdx.x & 63, w = threadIdx.x >> 6;
    if (lane == 0) red[w] = a;
    __syncthreads();
    if (threadIdx.x == 0)
        out[0] = ((red[0] + red[1]) + (red[2] + red[3])) * scale;
}

extern "C" void kernel_launch(void* const* d_in, const int* in_sizes, int n_in,
                              void* d_out, int out_size, void* d_ws, size_t ws_size,
                              hipStream_t stream) {
    const float* msi   = (const float*)d_in[0];
    const float* he    = (const float*)d_in[1];
    const int*   i_idx = (const int*)d_in[2];
    const int*   j_idx = (const int*)d_in[3];
    const int    NB    = in_sizes[2];
    float*       out   = (float*)d_out;

    unsigned short* rec  = (unsigned short*)d_ws;               // 512*512*112 B ~ 29.4 MB
    float*          part = (float*)((char*)d_ws + (32u << 20)); // partials at +32 MB

    const float scale = 1.0f / ((float)(PSZ * PSZ) * (float)(NB / 5));
    prep_kernel<<<IMG2 / 256, 256, 0, stream>>>(msi, he, rec);
    corr_loss_kernel<<<NB, 256, 0, stream>>>(rec, i_idx, j_idx, part);
    reduce_kernel<<<1, 256, 0, stream>>>(part, out, NB, scale);
}